// Round 3
// baseline (461.036 us; speedup 1.0000x reference)
//
#include <hip/hip_runtime.h>
#include <stdint.h>

// IncConv (version==3): out = zeros except 64x64 patch at [48,112)^2 holding
// conv3x3(in, w, pad=1, stride=1) + bias.  B=16, C_in=C_out=64, H=W=224.
//
// Round 3 structure:
//   1) hipMemsetAsync zeroes the whole output (rocclr fill hits 6.6 TB/s,
//      measured 82% of HBM peak in round-2 profile).
//   2) conv kernel (implicit GEMM, bf16 MFMA, 3-term hi/lo split) overwrites
//      the 64x64 patch. Stream order guarantees correctness.
// M = (b, pr, pc) = 65536, N = co = 64, K = (tap, ci) = 576.

#define BATCH 16
#define CI    64
#define CO    64
#define HW    224
#define PR0   48
#define PC0   48
#define PATCH 64

#define THREADS 512
#define NBLK    256

// LDS layout (units: shorts/bf16)
#define A_ROWS 6
#define A_COLS 66
#define A_CELL 40                         // 32 ci + 8 pad -> 80 B cell, bank-shift 20
#define A_SIZE (A_ROWS * A_COLS * A_CELL) // 15840
#define B_KPAD 296                        // 9 taps * 32 ci = 288, +8 pad -> 592 B row
#define B_SIZE (CO * B_KPAD)              // 18944
#define LDS_SHORTS (2 * (A_SIZE + B_SIZE))
#define LDS_BYTES  (LDS_SHORTS * 2)       // 139136 B

typedef __attribute__((ext_vector_type(8))) short short8v;
typedef __attribute__((ext_vector_type(4))) float f32x4;

union fu32 { float f; uint32_t u; };

__device__ __forceinline__ uint16_t f2bf(float x) {
    fu32 c; c.f = x;
    return (uint16_t)((c.u + 0x7FFFu + ((c.u >> 16) & 1u)) >> 16);  // RNE
}
__device__ __forceinline__ float bf2f(uint16_t h) {
    fu32 c; c.u = ((uint32_t)h) << 16; return c.f;
}

__global__ __launch_bounds__(THREADS, 1)
void inc_conv_mfma(const float* __restrict__ in, const float* __restrict__ wgt,
                   const float* __restrict__ bias, float* __restrict__ out) {
    extern __shared__ short smem[];
    short* Ah = smem;
    short* Al = smem + A_SIZE;
    short* Bh = smem + 2 * A_SIZE;
    short* Bl = smem + 2 * A_SIZE + B_SIZE;

    const int bid  = blockIdx.x;
    const int tid  = threadIdx.x;
    const int b    = bid >> 4;    // batch
    const int band = bid & 15;    // 4-row band of the 64-row patch

    const int lane = tid & 63;
    const int wv   = tid >> 6;    // wave 0..7
    const int l15  = lane & 15;
    const int kb   = lane >> 4;   // k-block 0..3
    const int prl  = wv >> 1;     // wave's patch row within band (0..3)
    const int pcb  = (wv & 1) << 5; // wave's patch col base (0 / 32)

    const int gr = PR0 - 1 + (band << 2); // staged input origin row (47..107)
    const int gc = PC0 - 1;               // staged input origin col (47)

    float bias_v[4];
    #pragma unroll
    for (int nf = 0; nf < 4; ++nf) bias_v[nf] = bias[nf * 16 + l15];

    f32x4 acc[2][4];
    #pragma unroll
    for (int mf = 0; mf < 2; ++mf)
        #pragma unroll
        for (int nf = 0; nf < 4; ++nf)
            acc[mf][nf] = (f32x4){0.f, 0.f, 0.f, 0.f};

    const int aBase = (prl * A_COLS + pcb + l15) * A_CELL + kb * 8;
    const int bBase = l15 * B_KPAD + kb * 8;

    for (int chunk = 0; chunk < 2; ++chunk) {
        const int ci0 = chunk << 5;   // ci chunk of 32
        if (chunk) __syncthreads();   // previous chunk's readers done

        // ---- stage A: 32 ci x 6 rows x 66 cols, split hi/lo ----
        for (int e = tid; e < 32 * A_ROWS * A_COLS; e += THREADS) {
            int s   = e / (A_ROWS * A_COLS);
            int rem = e - s * (A_ROWS * A_COLS);
            int r   = rem / A_COLS;
            int c   = rem - r * A_COLS;
            float x = in[((b * CI + ci0 + s) * HW + gr + r) * HW + gc + c];
            uint16_t h = f2bf(x);
            uint16_t l = f2bf(x - bf2f(h));
            int idx = (r * A_COLS + c) * A_CELL + s;
            Ah[idx] = (short)h;
            Al[idx] = (short)l;
        }
        // ---- stage B: w[n][ci0+cil][t] -> B[n][t*32+cil], split hi/lo ----
        for (int e = tid; e < CO * 32 * 9; e += THREADS) {
            int n   = e / 288;
            int rem = e - n * 288;
            int cil = rem / 9;
            int t   = rem - cil * 9;
            float x = wgt[(n * CI + ci0 + cil) * 9 + t];
            uint16_t h = f2bf(x);
            uint16_t l = f2bf(x - bf2f(h));
            int idx = n * B_KPAD + t * 32 + cil;
            Bh[idx] = (short)h;
            Bl[idx] = (short)l;
        }
        __syncthreads();

        // ---- MFMA over 9 taps, K-step = (tap, 32 ci) ----
        #pragma unroll
        for (int t = 0; t < 9; ++t) {
            const int kh = t / 3, kw = t - kh * 3;
            short8v ah[2], al[2], bh[4], bl[4];
            #pragma unroll
            for (int mf = 0; mf < 2; ++mf) {
                const int off = aBase + (kh * A_COLS + mf * 16 + kw) * A_CELL;
                ah[mf] = *(const short8v*)(Ah + off);
                al[mf] = *(const short8v*)(Al + off);
            }
            #pragma unroll
            for (int nf = 0; nf < 4; ++nf) {
                const int off = bBase + nf * 16 * B_KPAD + t * 32;
                bh[nf] = *(const short8v*)(Bh + off);
                bl[nf] = *(const short8v*)(Bl + off);
            }
            #pragma unroll
            for (int mf = 0; mf < 2; ++mf)
                #pragma unroll
                for (int nf = 0; nf < 4; ++nf) {
                    acc[mf][nf] = __builtin_amdgcn_mfma_f32_16x16x32_bf16(
                        ah[mf], bh[nf], acc[mf][nf], 0, 0, 0);
                    acc[mf][nf] = __builtin_amdgcn_mfma_f32_16x16x32_bf16(
                        ah[mf], bl[nf], acc[mf][nf], 0, 0, 0);
                    acc[mf][nf] = __builtin_amdgcn_mfma_f32_16x16x32_bf16(
                        al[mf], bh[nf], acc[mf][nf], 0, 0, 0);
                }
        }
    }

    // ---- epilogue: C/D layout col=lane&15 (N), row=(lane>>4)*4+reg (M) ----
    const int orow = PR0 + (band << 2) + prl;
    #pragma unroll
    for (int nf = 0; nf < 4; ++nf) {
        const int co = nf * 16 + l15;
        const float bv = bias_v[nf];
        #pragma unroll
        for (int mf = 0; mf < 2; ++mf) {
            const int ocol = PC0 + pcb + mf * 16 + kb * 4;
            f32x4 v = acc[mf][nf];
            float4 st = make_float4(v[0] + bv, v[1] + bv, v[2] + bv, v[3] + bv);
            *(float4*)&out[((b * CO + co) * HW + orow) * HW + ocol] = st;
        }
    }
}

extern "C" void kernel_launch(void* const* d_in, const int* in_sizes, int n_in,
                              void* d_out, int out_size, void* d_ws, size_t ws_size,
                              hipStream_t stream) {
    const float* in   = (const float*)d_in[0];
    const float* wgt  = (const float*)d_in[1];
    const float* bias = (const float*)d_in[2];
    float* out = (float*)d_out;

    // 1) zero the whole output at rocclr-fill bandwidth (capture-safe)
    hipMemsetAsync(out, 0, (size_t)out_size * sizeof(float), stream);

    // 2) conv patch kernel (overwrites the patch region after the memset)
    hipFuncSetAttribute((const void*)inc_conv_mfma,
                        hipFuncAttributeMaxDynamicSharedMemorySize, LDS_BYTES);
    inc_conv_mfma<<<NBLK, THREADS, LDS_BYTES, stream>>>(in, wgt, bias, out);
}

// Round 4
// 422.671 us; speedup vs baseline: 1.0908x; 1.0908x over previous
//
#include <hip/hip_runtime.h>
#include <stdint.h>

// IncConv (version==3): out = zeros except 64x64 patch at [48,112)^2 holding
// conv3x3(in, w, pad=1, stride=1) + bias.  B=16, C_in=C_out=64, H=W=224.
//
// Round 4:
//   1) hipMemsetAsync zeroes the output (measured 6.6 TB/s).
//   2) conv kernel, implicit GEMM on bf16 MFMA (3-term hi/lo split).
//      NEW: register-batched staging loads (float4) + chunk software
//      pipeline so HBM latency is exposed once, not per-element.

#define BATCH 16
#define CI    64
#define CO    64
#define HW    224
#define PR0   48
#define PC0   48

#define THREADS 512
#define NBLK    256

// LDS layout (units: shorts/bf16)
#define A_ROWS 6
#define A_COLS 72                         // cols 44..115 (f4-aligned), use 47..112
#define A_CELL 40                         // 32 ci + 8 pad -> 80 B, bank-stride 20
#define A_SIZE (A_ROWS * A_COLS * A_CELL) // 17280
#define B_KPAD 296                        // 9*32 + 8 pad -> 592 B row
#define B_SIZE (CO * B_KPAD)              // 18944
#define LDS_BYTES (2 * 2 * (A_SIZE + B_SIZE))  // 144896 B

#define A_F4 3456   // 32 ci * 6 rows * 18 float4
#define B_F4 4608   // 64 n * 72 float4

typedef __attribute__((ext_vector_type(8))) short short8v;
typedef __attribute__((ext_vector_type(4))) float f32x4;

union fu32 { float f; uint32_t u; };

__device__ __forceinline__ uint16_t f2bf(float x) {
    fu32 c; c.f = x;
    return (uint16_t)((c.u + 0x7FFFu + ((c.u >> 16) & 1u)) >> 16);  // RNE
}
__device__ __forceinline__ float bf2f(uint16_t h) {
    fu32 c; c.u = ((uint32_t)h) << 16; return c.f;
}

__global__ __launch_bounds__(THREADS, 1)
void inc_conv_mfma(const float* __restrict__ in, const float* __restrict__ wgt,
                   const float* __restrict__ bias, float* __restrict__ out) {
    extern __shared__ short smem[];
    short* Ah = smem;
    short* Al = smem + A_SIZE;
    short* Bh = smem + 2 * A_SIZE;
    short* Bl = smem + 2 * A_SIZE + B_SIZE;

    const int bid  = blockIdx.x;
    const int tid  = threadIdx.x;
    const int b    = bid >> 4;      // batch
    const int band = bid & 15;      // 4-row band of the 64-row patch

    const int lane = tid & 63;
    const int wv   = tid >> 6;      // wave 0..7
    const int l15  = lane & 15;
    const int kb   = lane >> 4;     // 0..3
    const int prl  = wv >> 1;       // wave's patch row in band (0..3)
    const int pcb  = (wv & 1) << 5; // wave's patch col base (0 / 32)

    const int gr = PR0 - 1 + (band << 2);  // staged input origin row

    float bias_v[4];
    #pragma unroll
    for (int nf = 0; nf < 4; ++nf) bias_v[nf] = bias[nf * 16 + l15];

    f32x4 acc[2][4];
    #pragma unroll
    for (int mf = 0; mf < 2; ++mf)
        #pragma unroll
        for (int nf = 0; nf < 4; ++nf)
            acc[mf][nf] = (f32x4){0.f, 0.f, 0.f, 0.f};

    const int aBase = (prl * A_COLS + pcb + l15 + 3) * A_CELL + kb * 8;
    const int bBase = l15 * B_KPAD + kb * 8;

    float4 aR[7], bR[9];

    // ---------- staging load: batch all global loads into registers ----------
    #define LOAD_CHUNK(ci0)                                                     \
        {                                                                       \
            _Pragma("unroll")                                                   \
            for (int i = 0; i < 7; ++i) {                                       \
                int e  = tid + i * THREADS;                                     \
                int ec = e < A_F4 ? e : A_F4 - 1;                               \
                int s   = ec / 108;                                             \
                int rem = ec - s * 108;                                         \
                int r   = rem / 18;                                             \
                int c4  = rem - r * 18;                                         \
                aR[i] = *(const float4*)&in[((b * CI + (ci0) + s) * HW + gr + r) \
                                            * HW + 44 + c4 * 4];                \
            }                                                                   \
            _Pragma("unroll")                                                   \
            for (int i = 0; i < 9; ++i) {                                       \
                int e = tid + i * THREADS;                                      \
                int n = e / 72;                                                 \
                int j = e - n * 72;                                             \
                bR[i] = *(const float4*)&wgt[(n * CI + (ci0)) * 9 + j * 4];     \
            }                                                                   \
        }

    // ---------- staging write: convert + LDS (vmcnt waits happen here) ----------
    #define WRITE_CHUNK()                                                       \
        {                                                                       \
            _Pragma("unroll")                                                   \
            for (int i = 0; i < 7; ++i) {                                       \
                int e = tid + i * THREADS;                                      \
                if (e < A_F4) {                                                 \
                    int s   = e / 108;                                          \
                    int rem = e - s * 108;                                      \
                    int r   = rem / 18;                                         \
                    int c4  = rem - r * 18;                                     \
                    _Pragma("unroll")                                           \
                    for (int jj = 0; jj < 4; ++jj) {                            \
                        float x = aR[i][jj];                                    \
                        uint16_t h = f2bf(x);                                   \
                        uint16_t l = f2bf(x - bf2f(h));                         \
                        int idx = (r * A_COLS + c4 * 4 + jj) * A_CELL + s;      \
                        Ah[idx] = (short)h;                                     \
                        Al[idx] = (short)l;                                     \
                    }                                                           \
                }                                                               \
            }                                                                   \
            _Pragma("unroll")                                                   \
            for (int i = 0; i < 9; ++i) {                                       \
                int e = tid + i * THREADS;                                      \
                int n = e / 72;                                                 \
                int j = e - n * 72;                                             \
                _Pragma("unroll")                                               \
                for (int jj = 0; jj < 4; ++jj) {                                \
                    int m   = j * 4 + jj;                                       \
                    int cil = m / 9;                                            \
                    int t   = m - cil * 9;                                      \
                    float x = bR[i][jj];                                        \
                    uint16_t h = f2bf(x);                                       \
                    uint16_t l = f2bf(x - bf2f(h));                             \
                    int idx = n * B_KPAD + t * 32 + cil;                        \
                    Bh[idx] = (short)h;                                         \
                    Bl[idx] = (short)l;                                         \
                }                                                               \
            }                                                                   \
        }

    // ---------- MFMA over 9 taps for one staged chunk ----------
    #define COMPUTE_CHUNK()                                                     \
        {                                                                       \
            _Pragma("unroll")                                                   \
            for (int t = 0; t < 9; ++t) {                                       \
                const int kh = t / 3, kw = t - kh * 3;                          \
                short8v ah[2], al[2], bh[4], bl[4];                             \
                _Pragma("unroll")                                               \
                for (int mf = 0; mf < 2; ++mf) {                                \
                    const int off = aBase + (kh * A_COLS + mf * 16 + kw) * A_CELL; \
                    ah[mf] = *(const short8v*)(Ah + off);                       \
                    al[mf] = *(const short8v*)(Al + off);                       \
                }                                                               \
                _Pragma("unroll")                                               \
                for (int nf = 0; nf < 4; ++nf) {                                \
                    const int off = bBase + nf * 16 * B_KPAD + t * 32;          \
                    bh[nf] = *(const short8v*)(Bh + off);                       \
                    bl[nf] = *(const short8v*)(Bl + off);                       \
                }                                                               \
                _Pragma("unroll")                                               \
                for (int mf = 0; mf < 2; ++mf)                                  \
                    _Pragma("unroll")                                           \
                    for (int nf = 0; nf < 4; ++nf) {                            \
                        acc[mf][nf] = __builtin_amdgcn_mfma_f32_16x16x32_bf16(  \
                            ah[mf], bh[nf], acc[mf][nf], 0, 0, 0);              \
                        acc[mf][nf] = __builtin_amdgcn_mfma_f32_16x16x32_bf16(  \
                            ah[mf], bl[nf], acc[mf][nf], 0, 0, 0);              \
                        acc[mf][nf] = __builtin_amdgcn_mfma_f32_16x16x32_bf16(  \
                            al[mf], bh[nf], acc[mf][nf], 0, 0, 0);              \
                    }                                                           \
            }                                                                   \
        }

    // ---------- software pipeline over the 2 ci-chunks ----------
    LOAD_CHUNK(0);
    WRITE_CHUNK();          // vmcnt waits here (nothing to hide yet)
    __syncthreads();
    LOAD_CHUNK(32);         // chunk-1 loads in flight during compute-0
    COMPUTE_CHUNK();
    __syncthreads();        // all chunk-0 readers done
    WRITE_CHUNK();          // waits hidden under compute-0 above
    __syncthreads();
    COMPUTE_CHUNK();

    // ---------- epilogue: C/D col=lane&15 (co), row=kb*4+reg (patch col) ----------
    const int orow = PR0 + (band << 2) + prl;
    #pragma unroll
    for (int nf = 0; nf < 4; ++nf) {
        const int co = nf * 16 + l15;
        const float bv = bias_v[nf];
        #pragma unroll
        for (int mf = 0; mf < 2; ++mf) {
            const int ocol = PC0 + pcb + mf * 16 + kb * 4;
            f32x4 v = acc[mf][nf];
            float4 st = make_float4(v[0] + bv, v[1] + bv, v[2] + bv, v[3] + bv);
            *(float4*)&out[((b * CO + co) * HW + orow) * HW + ocol] = st;
        }
    }
}

extern "C" void kernel_launch(void* const* d_in, const int* in_sizes, int n_in,
                              void* d_out, int out_size, void* d_ws, size_t ws_size,
                              hipStream_t stream) {
    const float* in   = (const float*)d_in[0];
    const float* wgt  = (const float*)d_in[1];
    const float* bias = (const float*)d_in[2];
    float* out = (float*)d_out;

    // 1) zero the whole output at rocclr-fill bandwidth (capture-safe)
    hipMemsetAsync(out, 0, (size_t)out_size * sizeof(float), stream);

    // 2) conv patch kernel
    hipFuncSetAttribute((const void*)inc_conv_mfma,
                        hipFuncAttributeMaxDynamicSharedMemorySize, LDS_BYTES);
    inc_conv_mfma<<<NBLK, THREADS, LDS_BYTES, stream>>>(in, wgt, bias, out);
}